// Round 3
// baseline (502.009 us; speedup 1.0000x reference)
//
#include <hip/hip_runtime.h>

typedef short short8 __attribute__((ext_vector_type(8)));
typedef float f32x4 __attribute__((ext_vector_type(4)));

__device__ __forceinline__ f32x4 mfma16(short8 a, short8 b, f32x4 c) {
    return __builtin_amdgcn_mfma_f32_16x16x32_bf16(a, b, c, 0, 0, 0);
}
__device__ __forceinline__ short f2bs(float f) {
    __bf16 h = (__bf16)f;
    return __builtin_bit_cast(short, h);
}
__device__ __forceinline__ void gld_lds16(const void* g, void* l) {
    __builtin_amdgcn_global_load_lds(
        (const __attribute__((address_space(1))) void*)g,
        (__attribute__((address_space(3))) void*)l, 16, 0, 0);
}

// ---------------------------------------------------------------------------
// fp32 -> bf16 bulk convert (8 elems/thread)
// ---------------------------------------------------------------------------
__global__ __launch_bounds__(256) void cvt_b16(const float* __restrict__ in,
                                               short* __restrict__ out) {
    const size_t i = ((size_t)blockIdx.x * 256 + threadIdx.x) * 8;
    const float4 v0 = *(const float4*)(in + i);
    const float4 v1 = *(const float4*)(in + i + 4);
    short8 s;
    s[0] = f2bs(v0.x); s[1] = f2bs(v0.y); s[2] = f2bs(v0.z); s[3] = f2bs(v0.w);
    s[4] = f2bs(v1.x); s[5] = f2bs(v1.y); s[6] = f2bs(v1.z); s[7] = f2bs(v1.w);
    *(short8*)(out + i) = s;
}

// ---------------------------------------------------------------------------
// MFMA GEMM-BT: C[r][n] = sum_k A[r][k]*W[n][k] + bias[n]
// A bf16 [8192][768] staged via global_load_lds_dwordx4 (linear dest,
// pre-swizzled source); W fp32 register-staged with the same XOR swizzle.
// 128x128 tile, BK=64, 12 K-steps, 32 MFMA per barrier pair.
// mode 0: C bf16 row-major; mode 1: C bf16 Vt[b][768][1024]; mode 2: C fp32.
// ---------------------------------------------------------------------------
__global__ __launch_bounds__(256) void gemm_mfma(const short* __restrict__ A,
                                                 const float* __restrict__ W,
                                                 const float* __restrict__ bias,
                                                 void* __restrict__ Cv,
                                                 int mode) {
    __shared__ short sA[128][64];
    __shared__ short sW[128][64];

    const int tid = threadIdx.x;
    const int wave = tid >> 6, lane = tid & 63;
    const int quad = lane >> 4, l16 = lane & 15;
    const int n0 = blockIdx.x * 128;
    const int r0 = blockIdx.y * 128;
    const int wm = (wave & 1) * 64;
    const int wn = (wave >> 1) * 64;

    const int lrow   = lane >> 3;                 // 0..7 (row within 8-row group)
    const int lchunk = (lane & 7) ^ lrow;         // pre-swizzled source chunk
    const short* Abase =
        A + (size_t)(r0 + wave * 32 + lrow) * 768 + lchunk * 8;

    const int wrow = tid >> 1;
    const int wseg = tid & 1;
    const float* Wbase = W + (size_t)(n0 + wrow) * 768 + wseg * 32;
    const int wsw = wrow & 7;                     // row swizzle key

    f32x4 acc[4][4];
#pragma unroll
    for (int mt = 0; mt < 4; ++mt)
#pragma unroll
        for (int nt = 0; nt < 4; ++nt) acc[mt][nt] = (f32x4){0.f, 0.f, 0.f, 0.f};

    for (int k0 = 0; k0 < 768; k0 += 64) {
        float4 wv[8];
#pragma unroll
        for (int j = 0; j < 8; ++j)
            wv[j] = *(const float4*)(Wbase + k0 + j * 4);

        __syncthreads();  // all waves done reading previous tile

#pragma unroll
        for (int i = 0; i < 4; ++i)
            gld_lds16(Abase + k0 + (size_t)i * 8 * 768,
                      &sA[(wave * 4 + i) * 8][0]);

#pragma unroll
        for (int c = 0; c < 4; ++c) {
            const float4 a = wv[2 * c], b = wv[2 * c + 1];
            short8 p;
            p[0] = f2bs(a.x); p[1] = f2bs(a.y); p[2] = f2bs(a.z); p[3] = f2bs(a.w);
            p[4] = f2bs(b.x); p[5] = f2bs(b.y); p[6] = f2bs(b.z); p[7] = f2bs(b.w);
            *(short8*)&sW[wrow][((wseg * 4 + c) ^ wsw) * 8] = p;
        }

        __syncthreads();  // compiler drains vmcnt(0)+lgkmcnt(0) here

#pragma unroll
        for (int ks = 0; ks < 2; ++ks) {
            short8 af[4], bf[4];
#pragma unroll
            for (int mt = 0; mt < 4; ++mt)
                af[mt] = *(const short8*)
                    &sA[wm + mt * 16 + l16][((ks * 4 + quad) ^ (l16 & 7)) * 8];
#pragma unroll
            for (int nt = 0; nt < 4; ++nt)
                bf[nt] = *(const short8*)
                    &sW[wn + nt * 16 + l16][((ks * 4 + quad) ^ (l16 & 7)) * 8];
#pragma unroll
            for (int mt = 0; mt < 4; ++mt)
#pragma unroll
                for (int nt = 0; nt < 4; ++nt)
                    acc[mt][nt] = mfma16(af[mt], bf[nt], acc[mt][nt]);
        }
    }

    short* Cs = (short*)Cv;
    float* Cf = (float*)Cv;
#pragma unroll
    for (int nt = 0; nt < 4; ++nt) {
        const int n = n0 + wn + nt * 16 + l16;
        const float bv = bias[n];
#pragma unroll
        for (int mt = 0; mt < 4; ++mt) {
#pragma unroll
            for (int rr = 0; rr < 4; ++rr) {
                const int row = r0 + wm + mt * 16 + quad * 4 + rr;
                const float val = acc[mt][nt][rr] + bv;
                if (mode == 0) {
                    Cs[(size_t)row * 768 + n] = f2bs(val);
                } else if (mode == 1) {
                    Cs[((size_t)(row >> 10) * 768 + n) * 1024 + (row & 1023)] = f2bs(val);
                } else {
                    Cf[(size_t)row * 768 + n] = val;
                }
            }
        }
    }
}

// ---------------------------------------------------------------------------
// Flash attention, no-max softmax. Block = (mtile128, h, b), 4 waves.
// ---------------------------------------------------------------------------
__global__ __launch_bounds__(256) void flash_att(const short* __restrict__ Q,
                                                 const short* __restrict__ K,
                                                 const short* __restrict__ Vt,
                                                 short* __restrict__ att,
                                                 float* __restrict__ linv) {
    const int mt = blockIdx.x;   // 0..7
    const int h  = blockIdx.y;
    const int b  = blockIdx.z;
    const int tid  = threadIdx.x;
    const int wave = tid >> 6;
    const int lane = tid & 63;
    const int quad = lane >> 4;
    const int l16  = lane & 15;

    __shared__ short Pl[4][32][40];  // 4 waves x 32 rows

    const int m0 = mt * 128 + wave * 32;
    const size_t brow = (size_t)b * 1024;

    short8 aq[2][3];
#pragma unroll
    for (int mf = 0; mf < 2; ++mf) {
        const short* qbase = Q + (brow + m0 + mf * 16 + l16) * 768 + h * 96 + quad * 8;
        aq[mf][0] = *(const short8*)(qbase);
        aq[mf][1] = *(const short8*)(qbase + 32);
        aq[mf][2] = *(const short8*)(qbase + 64);
    }

    f32x4 o[2][6];
#pragma unroll
    for (int mf = 0; mf < 2; ++mf)
#pragma unroll
        for (int nt = 0; nt < 6; ++nt) o[mf][nt] = (f32x4){0.f, 0.f, 0.f, 0.f};
    float li[2][4] = {};

    const float scale = 0.1020620726159657f;  // 1/sqrt(96)
    const short* kbase = K + brow * 768 + h * 96 + quad * 8;
    const short* vtb = Vt + ((size_t)b * 768 + h * 96) * 1024;

    short8 kcur[6], knxt[6];
    {
        const short* k0p = kbase + (size_t)l16 * 768;
        const short* k1p = k0p + 16 * 768;
        kcur[0] = *(const short8*)(k0p);
        kcur[1] = *(const short8*)(k0p + 32);
        kcur[2] = *(const short8*)(k0p + 64);
        kcur[3] = *(const short8*)(k1p);
        kcur[4] = *(const short8*)(k1p + 32);
        kcur[5] = *(const short8*)(k1p + 64);
    }

    for (int p0 = 0; p0 < 1024; p0 += 32) {
        short8 vt[6];
#pragma unroll
        for (int nt = 0; nt < 6; ++nt)
            vt[nt] = *(const short8*)(vtb + (size_t)(nt * 16 + l16) * 1024 +
                                      p0 + quad * 8);
        {
            const int pn = (p0 + 32) & 1023;
            const short* k0p = kbase + (size_t)(pn + l16) * 768;
            const short* k1p = k0p + 16 * 768;
            knxt[0] = *(const short8*)(k0p);
            knxt[1] = *(const short8*)(k0p + 32);
            knxt[2] = *(const short8*)(k0p + 64);
            knxt[3] = *(const short8*)(k1p);
            knxt[4] = *(const short8*)(k1p + 32);
            knxt[5] = *(const short8*)(k1p + 64);
        }

        float e0[2][4], e1[2][4];
#pragma unroll
        for (int mf = 0; mf < 2; ++mf) {
            f32x4 s0 = (f32x4){0.f, 0.f, 0.f, 0.f};
            f32x4 s1 = (f32x4){0.f, 0.f, 0.f, 0.f};
            s0 = mfma16(aq[mf][0], kcur[0], s0);
            s0 = mfma16(aq[mf][1], kcur[1], s0);
            s0 = mfma16(aq[mf][2], kcur[2], s0);
            s1 = mfma16(aq[mf][0], kcur[3], s1);
            s1 = mfma16(aq[mf][1], kcur[4], s1);
            s1 = mfma16(aq[mf][2], kcur[5], s1);
#pragma unroll
            for (int r = 0; r < 4; ++r) {
                e0[mf][r] = __expf(s0[r] * scale);
                e1[mf][r] = __expf(s1[r] * scale);
                li[mf][r] += e0[mf][r] + e1[mf][r];
            }
        }

#pragma unroll
        for (int mf = 0; mf < 2; ++mf)
#pragma unroll
            for (int r = 0; r < 4; ++r) {
                Pl[wave][mf * 16 + quad * 4 + r][l16]      = f2bs(e0[mf][r]);
                Pl[wave][mf * 16 + quad * 4 + r][l16 + 16] = f2bs(e1[mf][r]);
            }
        __builtin_amdgcn_s_waitcnt(0xc07f);  // lgkmcnt(0) only
#pragma unroll
        for (int mf = 0; mf < 2; ++mf) {
            const short4 plo = *(const short4*)&Pl[wave][mf * 16 + l16][quad * 8];
            const short4 phi = *(const short4*)&Pl[wave][mf * 16 + l16][quad * 8 + 4];
            const short8 ap = (short8){plo.x, plo.y, plo.z, plo.w,
                                       phi.x, phi.y, phi.z, phi.w};
#pragma unroll
            for (int nt = 0; nt < 6; ++nt) o[mf][nt] = mfma16(ap, vt[nt], o[mf][nt]);
        }

#pragma unroll
        for (int j = 0; j < 6; ++j) kcur[j] = knxt[j];
    }

#pragma unroll
    for (int mf = 0; mf < 2; ++mf) {
        float inv[4];
#pragma unroll
        for (int r = 0; r < 4; ++r) {
#pragma unroll
            for (int off = 1; off < 16; off <<= 1)
                li[mf][r] += __shfl_xor(li[mf][r], off, 16);
            inv[r] = 1.0f / li[mf][r];
        }
#pragma unroll
        for (int nt = 0; nt < 6; ++nt)
#pragma unroll
            for (int r = 0; r < 4; ++r)
                att[(brow + m0 + mf * 16 + quad * 4 + r) * 768 + h * 96 +
                    nt * 16 + l16] = f2bs(o[mf][nt][r] * inv[r]);
        if (l16 == 0) {
#pragma unroll
            for (int r = 0; r < 4; ++r)
                linv[(((size_t)b * 8 + h) << 10) + m0 + mf * 16 + quad * 4 + r] =
                    inv[r];
        }
    }
}

// ---------------------------------------------------------------------------
// Head-averaged attention map, round-2 restructure: flash_att-style explicit
// register ping-pong (A/B buffers, consume-current + prefetch-next) over the
// flat (pt, h) iteration space. Each wave: 16 m-rows x 32 p-cols per step,
// 6 MFMA + 8 exp2 per step, acc stored+rezeroed every 8 steps (h cycle).
// Grid (64 mt, 2 ps, 8 b) = 1024 blocks; launch_bounds(256,4) caps VGPR<=128.
// ---------------------------------------------------------------------------
__global__ __launch_bounds__(256, 4) void attn_avg4(const short* __restrict__ Q,
                                                    const short* __restrict__ K,
                                                    const float* __restrict__ linv,
                                                    float* __restrict__ avg) {
    const int mt = blockIdx.x;   // 16-row m tile
    const int ps = blockIdx.y;   // 512-col p half
    const int b  = blockIdx.z;
    const int tid  = threadIdx.x;
    const int wave = tid >> 6;
    const int lane = tid & 63;
    const int quad = lane >> 4;
    const int l16  = lane & 15;

    const int m0 = mt * 16;
    const size_t brow = (size_t)b * 1024;
    const float scale2 = 0.14724445f;  // (1/sqrt(96)) * log2(e)

    const short* Kb_ = K + brow * 768 + quad * 8;             // + row*768 + h*96
    const short* Qb_ = Q + (brow + m0 + l16) * 768 + quad * 8;  // + h*96
    const float* Lb_ = linv + (((size_t)b * 8) << 10) + m0 + quad * 4;  // + (h<<10)
    const int pw = ps * 512 + wave * 32;

    short8 kA[6], kB[6], qA[3], qB[3];
    f32x4 ilA, ilB;
    f32x4 acc0 = (f32x4){0.f, 0.f, 0.f, 0.f};
    f32x4 acc1 = (f32x4){0.f, 0.f, 0.f, 0.f};

    {   // prologue: load buffers for it=0 (pt=0, h=0)
        const short* kp = Kb_ + (size_t)(pw + l16) * 768;
        kA[0] = *(const short8*)(kp);
        kA[1] = *(const short8*)(kp + 32);
        kA[2] = *(const short8*)(kp + 64);
        kA[3] = *(const short8*)(kp + 16 * 768);
        kA[4] = *(const short8*)(kp + 16 * 768 + 32);
        kA[5] = *(const short8*)(kp + 16 * 768 + 64);
        qA[0] = *(const short8*)(Qb_);
        qA[1] = *(const short8*)(Qb_ + 32);
        qA[2] = *(const short8*)(Qb_ + 64);
        ilA = 0.125f * *(const f32x4*)(Lb_);
    }

#define AVG_STEP(KC, QC, ILC, KN, QN, ILN, IT)                                   \
    {                                                                            \
        const int nit = ((IT) + 1) & 31;                                         \
        const int nh  = nit & 7;                                                 \
        const int npb = pw + (nit >> 3) * 128;                                   \
        const short* nkp = Kb_ + (size_t)(npb + l16) * 768 + nh * 96;            \
        KN[0] = *(const short8*)(nkp);                                           \
        KN[1] = *(const short8*)(nkp + 32);                                      \
        KN[2] = *(const short8*)(nkp + 64);                                      \
        KN[3] = *(const short8*)(nkp + 16 * 768);                                \
        KN[4] = *(const short8*)(nkp + 16 * 768 + 32);                           \
        KN[5] = *(const short8*)(nkp + 16 * 768 + 64);                           \
        QN[0] = *(const short8*)(Qb_ + nh * 96);                                 \
        QN[1] = *(const short8*)(Qb_ + nh * 96 + 32);                            \
        QN[2] = *(const short8*)(Qb_ + nh * 96 + 64);                            \
        ILN = 0.125f * *(const f32x4*)(Lb_ + ((size_t)nh << 10));                \
        f32x4 s0 = (f32x4){0.f, 0.f, 0.f, 0.f};                                  \
        f32x4 s1 = (f32x4){0.f, 0.f, 0.f, 0.f};                                  \
        s0 = mfma16(QC[0], KC[0], s0);                                           \
        s0 = mfma16(QC[1], KC[1], s0);                                           \
        s0 = mfma16(QC[2], KC[2], s0);                                           \
        s1 = mfma16(QC[0], KC[3], s1);                                           \
        s1 = mfma16(QC[1], KC[4], s1);                                           \
        s1 = mfma16(QC[2], KC[5], s1);                                           \
        _Pragma("unroll")                                                        \
        for (int r = 0; r < 4; ++r) {                                            \
            acc0[r] += __builtin_exp2f(s0[r] * scale2) * ILC[r];                 \
            acc1[r] += __builtin_exp2f(s1[r] * scale2) * ILC[r];                 \
        }                                                                        \
        if (((IT) & 7) == 7) {                                                   \
            const int pb = pw + ((IT) >> 3) * 128;                               \
            _Pragma("unroll")                                                    \
            for (int r = 0; r < 4; ++r) {                                        \
                avg[(brow + m0 + quad * 4 + r) * 1024 + pb + l16] = acc0[r];     \
                avg[(brow + m0 + quad * 4 + r) * 1024 + pb + 16 + l16] = acc1[r];\
            }                                                                    \
            acc0 = (f32x4){0.f, 0.f, 0.f, 0.f};                                  \
            acc1 = (f32x4){0.f, 0.f, 0.f, 0.f};                                  \
        }                                                                        \
    }

#pragma unroll 1
    for (int it = 0; it < 32; it += 2) {
        AVG_STEP(kA, qA, ilA, kB, qB, ilB, it)
        AVG_STEP(kB, qB, ilB, kA, qA, ilA, it + 1)
    }
#undef AVG_STEP
}

extern "C" void kernel_launch(void* const* d_in, const int* in_sizes, int n_in,
                              void* d_out, int out_size, void* d_ws, size_t ws_size,
                              hipStream_t stream) {
    (void)in_sizes; (void)n_in; (void)out_size; (void)d_ws; (void)ws_size;

    float* mam = (float*)d_in[0];
    float* pat = (float*)d_in[1];
    const float* qw = (const float*)d_in[2];
    const float* qb = (const float*)d_in[3];
    const float* kw = (const float*)d_in[4];
    const float* kb = (const float*)d_in[5];
    const float* vw = (const float*)d_in[6];
    const float* vb = (const float*)d_in[7];
    const float* ow = (const float*)d_in[8];
    const float* ob = (const float*)d_in[9];

    const size_t NTOK = (size_t)8 * 1024 * 768;
    float* out_att = (float*)d_out;
    float* out_avg = out_att + NTOK;

    short* Am = (short*)d_out;           // bf16 mammo  @ out_att head (dead after Q-proj)
    short* Ap = (short*)out_avg;         // bf16 patho  @ out_avg head (dead after V-proj)
    short* Qb = (short*)mam;             // bf16 Q      @ mammo[0:NTOK]
    short* Kb = Qb + NTOK;               // bf16 K      @ mammo[NTOK:2*NTOK]
    short* Vt = (short*)pat;             // bf16 Vt     @ patho[0:NTOK]
    short* Ab = Vt + NTOK;               // bf16 att    @ patho[NTOK:2*NTOK]
    float* LV = (float*)(Am + NTOK);     // 1/l (256KB) @ out_att tail (dead before O-proj)

    dim3 bb(256), gg(6, 64);
    cvt_b16<<<3072, bb, 0, stream>>>(mam, Am);
    cvt_b16<<<3072, bb, 0, stream>>>(pat, Ap);
    gemm_mfma<<<gg, bb, 0, stream>>>(Am, qw, qb, Qb, 0);
    gemm_mfma<<<gg, bb, 0, stream>>>(Ap, kw, kb, Kb, 0);
    gemm_mfma<<<gg, bb, 0, stream>>>(Ap, vw, vb, Vt, 1);

    flash_att<<<dim3(8, 8, 8), bb, 0, stream>>>(Qb, Kb, Vt, Ab, LV);
    attn_avg4<<<dim3(64, 2, 8), bb, 0, stream>>>(Qb, Kb, LV, out_avg);

    gemm_mfma<<<gg, bb, 0, stream>>>(Ab, ow, ob, out_att, 2);
}

// Round 4
// 433.418 us; speedup vs baseline: 1.1583x; 1.1583x over previous
//
#include <hip/hip_runtime.h>

typedef short short8 __attribute__((ext_vector_type(8)));
typedef float f32x4 __attribute__((ext_vector_type(4)));

__device__ __forceinline__ f32x4 mfma16(short8 a, short8 b, f32x4 c) {
    return __builtin_amdgcn_mfma_f32_16x16x32_bf16(a, b, c, 0, 0, 0);
}
__device__ __forceinline__ short f2bs(float f) {
    __bf16 h = (__bf16)f;
    return __builtin_bit_cast(short, h);
}
__device__ __forceinline__ void gld_lds16(const void* g, void* l) {
    __builtin_amdgcn_global_load_lds(
        (const __attribute__((address_space(1))) void*)g,
        (__attribute__((address_space(3))) void*)l, 16, 0, 0);
}

// ---------------------------------------------------------------------------
// fp32 -> bf16 bulk convert (8 elems/thread)
// ---------------------------------------------------------------------------
__global__ __launch_bounds__(256) void cvt_b16(const float* __restrict__ in,
                                               short* __restrict__ out) {
    const size_t i = ((size_t)blockIdx.x * 256 + threadIdx.x) * 8;
    const float4 v0 = *(const float4*)(in + i);
    const float4 v1 = *(const float4*)(in + i + 4);
    short8 s;
    s[0] = f2bs(v0.x); s[1] = f2bs(v0.y); s[2] = f2bs(v0.z); s[3] = f2bs(v0.w);
    s[4] = f2bs(v1.x); s[5] = f2bs(v1.y); s[6] = f2bs(v1.z); s[7] = f2bs(v1.w);
    *(short8*)(out + i) = s;
}

// ---------------------------------------------------------------------------
// MFMA GEMM-BT: C[r][n] = sum_k A[r][k]*W[n][k] + bias[n]
// A bf16 [8192][768] staged via global_load_lds_dwordx4 (linear dest,
// pre-swizzled source); W fp32 register-staged with the same XOR swizzle.
// 128x128 tile, BK=64, 12 K-steps, 32 MFMA per barrier pair.
// mode 0: C bf16 row-major; mode 1: C bf16 Vt[b][768][1024]; mode 2: C fp32.
// ---------------------------------------------------------------------------
__global__ __launch_bounds__(256) void gemm_mfma(const short* __restrict__ A,
                                                 const float* __restrict__ W,
                                                 const float* __restrict__ bias,
                                                 void* __restrict__ Cv,
                                                 int mode) {
    __shared__ short sA[128][64];
    __shared__ short sW[128][64];

    const int tid = threadIdx.x;
    const int wave = tid >> 6, lane = tid & 63;
    const int quad = lane >> 4, l16 = lane & 15;
    const int n0 = blockIdx.x * 128;
    const int r0 = blockIdx.y * 128;
    const int wm = (wave & 1) * 64;
    const int wn = (wave >> 1) * 64;

    const int lrow   = lane >> 3;                 // 0..7 (row within 8-row group)
    const int lchunk = (lane & 7) ^ lrow;         // pre-swizzled source chunk
    const short* Abase =
        A + (size_t)(r0 + wave * 32 + lrow) * 768 + lchunk * 8;

    const int wrow = tid >> 1;
    const int wseg = tid & 1;
    const float* Wbase = W + (size_t)(n0 + wrow) * 768 + wseg * 32;
    const int wsw = wrow & 7;                     // row swizzle key

    f32x4 acc[4][4];
#pragma unroll
    for (int mt = 0; mt < 4; ++mt)
#pragma unroll
        for (int nt = 0; nt < 4; ++nt) acc[mt][nt] = (f32x4){0.f, 0.f, 0.f, 0.f};

    for (int k0 = 0; k0 < 768; k0 += 64) {
        float4 wv[8];
#pragma unroll
        for (int j = 0; j < 8; ++j)
            wv[j] = *(const float4*)(Wbase + k0 + j * 4);

        __syncthreads();  // all waves done reading previous tile

#pragma unroll
        for (int i = 0; i < 4; ++i)
            gld_lds16(Abase + k0 + (size_t)i * 8 * 768,
                      &sA[(wave * 4 + i) * 8][0]);

#pragma unroll
        for (int c = 0; c < 4; ++c) {
            const float4 a = wv[2 * c], b = wv[2 * c + 1];
            short8 p;
            p[0] = f2bs(a.x); p[1] = f2bs(a.y); p[2] = f2bs(a.z); p[3] = f2bs(a.w);
            p[4] = f2bs(b.x); p[5] = f2bs(b.y); p[6] = f2bs(b.z); p[7] = f2bs(b.w);
            *(short8*)&sW[wrow][((wseg * 4 + c) ^ wsw) * 8] = p;
        }

        __syncthreads();  // compiler drains vmcnt(0)+lgkmcnt(0) here

#pragma unroll
        for (int ks = 0; ks < 2; ++ks) {
            short8 af[4], bf[4];
#pragma unroll
            for (int mt = 0; mt < 4; ++mt)
                af[mt] = *(const short8*)
                    &sA[wm + mt * 16 + l16][((ks * 4 + quad) ^ (l16 & 7)) * 8];
#pragma unroll
            for (int nt = 0; nt < 4; ++nt)
                bf[nt] = *(const short8*)
                    &sW[wn + nt * 16 + l16][((ks * 4 + quad) ^ (l16 & 7)) * 8];
#pragma unroll
            for (int mt = 0; mt < 4; ++mt)
#pragma unroll
                for (int nt = 0; nt < 4; ++nt)
                    acc[mt][nt] = mfma16(af[mt], bf[nt], acc[mt][nt]);
        }
    }

    short* Cs = (short*)Cv;
    float* Cf = (float*)Cv;
#pragma unroll
    for (int nt = 0; nt < 4; ++nt) {
        const int n = n0 + wn + nt * 16 + l16;
        const float bv = bias[n];
#pragma unroll
        for (int mt = 0; mt < 4; ++mt) {
#pragma unroll
            for (int rr = 0; rr < 4; ++rr) {
                const int row = r0 + wm + mt * 16 + quad * 4 + rr;
                const float val = acc[mt][nt][rr] + bv;
                if (mode == 0) {
                    Cs[(size_t)row * 768 + n] = f2bs(val);
                } else if (mode == 1) {
                    Cs[((size_t)(row >> 10) * 768 + n) * 1024 + (row & 1023)] = f2bs(val);
                } else {
                    Cf[(size_t)row * 768 + n] = val;
                }
            }
        }
    }
}

// ---------------------------------------------------------------------------
// Flash attention, no-max softmax. Block = (mtile128, h, b), 4 waves.
// ---------------------------------------------------------------------------
__global__ __launch_bounds__(256) void flash_att(const short* __restrict__ Q,
                                                 const short* __restrict__ K,
                                                 const short* __restrict__ Vt,
                                                 short* __restrict__ att,
                                                 float* __restrict__ linv) {
    const int mt = blockIdx.x;   // 0..7
    const int h  = blockIdx.y;
    const int b  = blockIdx.z;
    const int tid  = threadIdx.x;
    const int wave = tid >> 6;
    const int lane = tid & 63;
    const int quad = lane >> 4;
    const int l16  = lane & 15;

    __shared__ short Pl[4][32][40];  // 4 waves x 32 rows

    const int m0 = mt * 128 + wave * 32;
    const size_t brow = (size_t)b * 1024;

    short8 aq[2][3];
#pragma unroll
    for (int mf = 0; mf < 2; ++mf) {
        const short* qbase = Q + (brow + m0 + mf * 16 + l16) * 768 + h * 96 + quad * 8;
        aq[mf][0] = *(const short8*)(qbase);
        aq[mf][1] = *(const short8*)(qbase + 32);
        aq[mf][2] = *(const short8*)(qbase + 64);
    }

    f32x4 o[2][6];
#pragma unroll
    for (int mf = 0; mf < 2; ++mf)
#pragma unroll
        for (int nt = 0; nt < 6; ++nt) o[mf][nt] = (f32x4){0.f, 0.f, 0.f, 0.f};
    float li[2][4] = {};

    const float scale = 0.1020620726159657f;  // 1/sqrt(96)
    const short* kbase = K + brow * 768 + h * 96 + quad * 8;
    const short* vtb = Vt + ((size_t)b * 768 + h * 96) * 1024;

    short8 kcur[6], knxt[6];
    {
        const short* k0p = kbase + (size_t)l16 * 768;
        const short* k1p = k0p + 16 * 768;
        kcur[0] = *(const short8*)(k0p);
        kcur[1] = *(const short8*)(k0p + 32);
        kcur[2] = *(const short8*)(k0p + 64);
        kcur[3] = *(const short8*)(k1p);
        kcur[4] = *(const short8*)(k1p + 32);
        kcur[5] = *(const short8*)(k1p + 64);
    }

    for (int p0 = 0; p0 < 1024; p0 += 32) {
        short8 vt[6];
#pragma unroll
        for (int nt = 0; nt < 6; ++nt)
            vt[nt] = *(const short8*)(vtb + (size_t)(nt * 16 + l16) * 1024 +
                                      p0 + quad * 8);
        {
            const int pn = (p0 + 32) & 1023;
            const short* k0p = kbase + (size_t)(pn + l16) * 768;
            const short* k1p = k0p + 16 * 768;
            knxt[0] = *(const short8*)(k0p);
            knxt[1] = *(const short8*)(k0p + 32);
            knxt[2] = *(const short8*)(k0p + 64);
            knxt[3] = *(const short8*)(k1p);
            knxt[4] = *(const short8*)(k1p + 32);
            knxt[5] = *(const short8*)(k1p + 64);
        }

        float e0[2][4], e1[2][4];
#pragma unroll
        for (int mf = 0; mf < 2; ++mf) {
            f32x4 s0 = (f32x4){0.f, 0.f, 0.f, 0.f};
            f32x4 s1 = (f32x4){0.f, 0.f, 0.f, 0.f};
            s0 = mfma16(aq[mf][0], kcur[0], s0);
            s0 = mfma16(aq[mf][1], kcur[1], s0);
            s0 = mfma16(aq[mf][2], kcur[2], s0);
            s1 = mfma16(aq[mf][0], kcur[3], s1);
            s1 = mfma16(aq[mf][1], kcur[4], s1);
            s1 = mfma16(aq[mf][2], kcur[5], s1);
#pragma unroll
            for (int r = 0; r < 4; ++r) {
                e0[mf][r] = __expf(s0[r] * scale);
                e1[mf][r] = __expf(s1[r] * scale);
                li[mf][r] += e0[mf][r] + e1[mf][r];
            }
        }

#pragma unroll
        for (int mf = 0; mf < 2; ++mf)
#pragma unroll
            for (int r = 0; r < 4; ++r) {
                Pl[wave][mf * 16 + quad * 4 + r][l16]      = f2bs(e0[mf][r]);
                Pl[wave][mf * 16 + quad * 4 + r][l16 + 16] = f2bs(e1[mf][r]);
            }
        __builtin_amdgcn_s_waitcnt(0xc07f);  // lgkmcnt(0) only
#pragma unroll
        for (int mf = 0; mf < 2; ++mf) {
            const short4 plo = *(const short4*)&Pl[wave][mf * 16 + l16][quad * 8];
            const short4 phi = *(const short4*)&Pl[wave][mf * 16 + l16][quad * 8 + 4];
            const short8 ap = (short8){plo.x, plo.y, plo.z, plo.w,
                                       phi.x, phi.y, phi.z, phi.w};
#pragma unroll
            for (int nt = 0; nt < 6; ++nt) o[mf][nt] = mfma16(ap, vt[nt], o[mf][nt]);
        }

#pragma unroll
        for (int j = 0; j < 6; ++j) kcur[j] = knxt[j];
    }

#pragma unroll
    for (int mf = 0; mf < 2; ++mf) {
        float inv[4];
#pragma unroll
        for (int r = 0; r < 4; ++r) {
#pragma unroll
            for (int off = 1; off < 16; off <<= 1)
                li[mf][r] += __shfl_xor(li[mf][r], off, 16);
            inv[r] = 1.0f / li[mf][r];
        }
#pragma unroll
        for (int nt = 0; nt < 6; ++nt)
#pragma unroll
            for (int r = 0; r < 4; ++r)
                att[(brow + m0 + mf * 16 + quad * 4 + r) * 768 + h * 96 +
                    nt * 16 + l16] = f2bs(o[mf][nt][r] * inv[r]);
        if (l16 == 0) {
#pragma unroll
            for (int r = 0; r < 4; ++r)
                linv[(((size_t)b * 8 + h) << 10) + m0 + mf * 16 + quad * 4 + r] =
                    inv[r];
        }
    }
}

// ---------------------------------------------------------------------------
// Head-averaged attention map, round-3: gemm_mfma's proven 2-barrier DMA
// structure. avg = sum_h exp2(scale2 * Q_h K_h^T) * (linv_h/8) is a 128x128
// GEMM tile over 8 K-steps (BK=96 = one head), exp folded between steps.
// Q and K tiles (both bf16) staged via global_load_lds into chunk-plane
// LDS layout [12 chunks][128 rows][8 shorts]: DMA dest is linear per
// instruction (plane base + lane*16B), fragment ds_read_b128 hits every
// bank exactly 8x per wave (= the 1KB/wave floor, conflict-free).
// Grid (8 pt, 8 mt, 8 b) = 512 blocks, 4 waves, each wave 64m x 64p.
// ---------------------------------------------------------------------------
__global__ __launch_bounds__(256) void attn_avg5(const short* __restrict__ Q,
                                                 const short* __restrict__ K,
                                                 const float* __restrict__ linv,
                                                 float* __restrict__ avg) {
    __shared__ short sQ[12][128][8];  // 24 KB
    __shared__ short sK[12][128][8];  // 24 KB

    const int pt = blockIdx.x;
    const int mt = blockIdx.y;
    const int b  = blockIdx.z;
    const int tid  = threadIdx.x;
    const int wave = tid >> 6;
    const int lane = tid & 63;
    const int quad = lane >> 4;
    const int l16  = lane & 15;

    const int m0 = mt * 128;
    const int p0 = pt * 128;
    const size_t brow = (size_t)b * 1024;
    const int wm = (wave & 1) * 64;
    const int wn = (wave >> 1) * 64;
    const float scale2 = 0.14724445f;  // (1/sqrt(96)) * log2(e)

    // per-lane DMA source bases (row within 64-row half = lane)
    const short* Qsrc = Q + (brow + m0 + lane) * 768;
    const short* Ksrc = K + (brow + p0 + lane) * 768;
    const float* Lb_  = linv + (((size_t)b * 8) << 10) + m0 + wm + quad * 4;

    f32x4 acc[4][4];
#pragma unroll
    for (int x = 0; x < 4; ++x)
#pragma unroll
        for (int y = 0; y < 4; ++y) acc[x][y] = (f32x4){0.f, 0.f, 0.f, 0.f};

#pragma unroll 1
    for (int h = 0; h < 8; ++h) {
        __syncthreads();  // previous step's fragment reads complete

        // 24 DMA instrs per tensor, 6 per wave: j = wave*6+i, plane = j>>1,
        // half = j&1. dest linear (plane base + half*1KB + lane*16B).
#pragma unroll
        for (int i = 0; i < 6; ++i) {
            const int j = wave * 6 + i;
            const int c = j >> 1, half = j & 1;
            gld_lds16(Qsrc + (size_t)(half * 64) * 768 + h * 96 + c * 8,
                      &sQ[c][half * 64][0]);
            gld_lds16(Ksrc + (size_t)(half * 64) * 768 + h * 96 + c * 8,
                      &sK[c][half * 64][0]);
        }

        // 1/(8*l) rows for this head (global, overlaps DMA)
        f32x4 il[4];
#pragma unroll
        for (int x = 0; x < 4; ++x)
            il[x] = 0.125f * *(const f32x4*)(Lb_ + ((size_t)h << 10) + x * 16);

        __syncthreads();  // drains vmcnt: LDS tiles ready

        short8 af[4][3], bf[4][3];
#pragma unroll
        for (int x = 0; x < 4; ++x)
#pragma unroll
            for (int kc = 0; kc < 3; ++kc) {
                af[x][kc] = *(const short8*)&sQ[kc * 4 + quad][wm + x * 16 + l16][0];
                bf[x][kc] = *(const short8*)&sK[kc * 4 + quad][wn + x * 16 + l16][0];
            }

#pragma unroll
        for (int x = 0; x < 4; ++x)
#pragma unroll
            for (int y = 0; y < 4; ++y) {
                f32x4 s = (f32x4){0.f, 0.f, 0.f, 0.f};
                s = mfma16(af[x][0], bf[y][0], s);
                s = mfma16(af[x][1], bf[y][1], s);
                s = mfma16(af[x][2], bf[y][2], s);
#pragma unroll
                for (int r = 0; r < 4; ++r)
                    acc[x][y][r] += __builtin_exp2f(s[r] * scale2) * il[x][r];
            }
    }

#pragma unroll
    for (int x = 0; x < 4; ++x)
#pragma unroll
        for (int y = 0; y < 4; ++y)
#pragma unroll
            for (int r = 0; r < 4; ++r)
                avg[(brow + m0 + wm + x * 16 + quad * 4 + r) * 1024 +
                    p0 + wn + y * 16 + l16] = acc[x][y][r];
}

extern "C" void kernel_launch(void* const* d_in, const int* in_sizes, int n_in,
                              void* d_out, int out_size, void* d_ws, size_t ws_size,
                              hipStream_t stream) {
    (void)in_sizes; (void)n_in; (void)out_size; (void)d_ws; (void)ws_size;

    float* mam = (float*)d_in[0];
    float* pat = (float*)d_in[1];
    const float* qw = (const float*)d_in[2];
    const float* qb = (const float*)d_in[3];
    const float* kw = (const float*)d_in[4];
    const float* kb = (const float*)d_in[5];
    const float* vw = (const float*)d_in[6];
    const float* vb = (const float*)d_in[7];
    const float* ow = (const float*)d_in[8];
    const float* ob = (const float*)d_in[9];

    const size_t NTOK = (size_t)8 * 1024 * 768;
    float* out_att = (float*)d_out;
    float* out_avg = out_att + NTOK;

    short* Am = (short*)d_out;           // bf16 mammo  @ out_att head (dead after Q-proj)
    short* Ap = (short*)out_avg;         // bf16 patho  @ out_avg head (dead after V-proj)
    short* Qb = (short*)mam;             // bf16 Q      @ mammo[0:NTOK]
    short* Kb = Qb + NTOK;               // bf16 K      @ mammo[NTOK:2*NTOK]
    short* Vt = (short*)pat;             // bf16 Vt     @ patho[0:NTOK]
    short* Ab = Vt + NTOK;               // bf16 att    @ patho[NTOK:2*NTOK]
    float* LV = (float*)(Am + NTOK);     // 1/l (256KB) @ out_att tail (dead before O-proj)

    dim3 bb(256), gg(6, 64);
    cvt_b16<<<3072, bb, 0, stream>>>(mam, Am);
    cvt_b16<<<3072, bb, 0, stream>>>(pat, Ap);
    gemm_mfma<<<gg, bb, 0, stream>>>(Am, qw, qb, Qb, 0);
    gemm_mfma<<<gg, bb, 0, stream>>>(Ap, kw, kb, Kb, 0);
    gemm_mfma<<<gg, bb, 0, stream>>>(Ap, vw, vb, Vt, 1);

    flash_att<<<dim3(8, 8, 8), bb, 0, stream>>>(Qb, Kb, Vt, Ab, LV);
    attn_avg5<<<dim3(8, 8, 8), bb, 0, stream>>>(Qb, Kb, LV, out_avg);

    gemm_mfma<<<gg, bb, 0, stream>>>(Ab, ow, ob, out_att, 2);
}